// Round 13
// baseline (440.426 us; speedup 1.0000x reference)
//
#include <hip/hip_runtime.h>
#include <math.h>

// Problem dims (fixed by the reference)
#define S_DIM 4096
#define H_DIM 4096
#define HC_N 4
#define HD_DIM 16384   // HC_N * H_DIM
#define MIXN 24        // (2+HC)*HC
#define SINK_IT 20
#define KSPL 64        // K-split for mixgemm (256 k per slice)

typedef float f32x4 __attribute__((ext_vector_type(4)));
typedef __bf16 bf16x8 __attribute__((ext_vector_type(8)));
typedef unsigned short u16x8 __attribute__((ext_vector_type(8)));
typedef unsigned short u16x4 __attribute__((ext_vector_type(4)));

__device__ __forceinline__ unsigned short f2bf(float f) {
  unsigned u = __builtin_bit_cast(unsigned, f);
  u += 0x7FFFu + ((u >> 16) & 1u);   // round-to-nearest-even
  return (unsigned short)(u >> 16);
}
__device__ __forceinline__ float bf2f(unsigned short h) {
  return __builtin_bit_cast(float, (unsigned)h << 16);
}

// ---------------------------------------------------------------------------
// K0: fp32->bf16: w_inner (blocks 0..8191), hc_fn (8192..8383), fnb zero-pad
// rows 24..31 (8384..8447).
__global__ __launch_bounds__(256) void k_w2bf(const float* __restrict__ w,
                                              unsigned short* __restrict__ wb,
                                              const float* __restrict__ fn,
                                              unsigned short* __restrict__ fnb) {
  const int b = blockIdx.x;
  if (b < 8192) {
    const size_t i = (size_t)b * 2048 + threadIdx.x * 8;
    f32x4 a = *(const f32x4*)(w + i);
    f32x4 c = *(const f32x4*)(w + i + 4);
    u16x8 o;
    o[0] = f2bf(a.x); o[1] = f2bf(a.y); o[2] = f2bf(a.z); o[3] = f2bf(a.w);
    o[4] = f2bf(c.x); o[5] = f2bf(c.y); o[6] = f2bf(c.z); o[7] = f2bf(c.w);
    *(u16x8*)(wb + i) = o;
  } else if (b < 8384) {
    const size_t i = (size_t)(b - 8192) * 2048 + threadIdx.x * 8;  // < 393216
    f32x4 a = *(const f32x4*)(fn + i);
    f32x4 c = *(const f32x4*)(fn + i + 4);
    u16x8 o;
    o[0] = f2bf(a.x); o[1] = f2bf(a.y); o[2] = f2bf(a.z); o[3] = f2bf(a.w);
    o[4] = f2bf(c.x); o[5] = f2bf(c.y); o[6] = f2bf(c.z); o[7] = f2bf(c.w);
    *(u16x8*)(fnb + i) = o;
  } else {
    const size_t i = 393216 + (size_t)(b - 8384) * 2048 + threadIdx.x * 8;
    u16x8 o = {0, 0, 0, 0, 0, 0, 0, 0};
    *(u16x8*)(fnb + i) = o;
  }
}

// ---------------------------------------------------------------------------
// K1: mixes as MFMA GEMM over K-slices of 256 (KSPL=64 -> 2048 blocks, 8/CU
// for TLP — the R11 win mechanism; R12's 1024 blocks ran ~90us vs 41 floor).
// Partials transposed to [p][row][24] / [p][row] for coalesced reduction.
// WH path additionally writes the in-register bf16 conversion of hs out to
// hsb (each hs element is loaded exactly once chip-wide here), halving the
// hs traffic of the two downstream readers (k_rn_bf, k_expand_bf).
template<bool WH>
__global__ __launch_bounds__(256) void k_mixgemm(const float* __restrict__ hs,
                                                 const unsigned short* __restrict__ fnb,
                                                 float* __restrict__ mixpart,
                                                 float* __restrict__ sumsqpart,
                                                 unsigned short* __restrict__ hsb) {
  const int rt = blockIdx.x;    // row tile: 128 rows
  const int p = blockIdx.y;     // k slice: 256 k
  const int tid = threadIdx.x, lane = tid & 63, wave = tid >> 6;
  const int r16 = lane & 15, kq = lane >> 4;
  const int row0 = rt * 128 + wave * 32;
  const size_t kbase = (size_t)p * 256 + kq * 8;

  f32x4 acc[2][2];
  f32x4 zero = {0.f, 0.f, 0.f, 0.f};
  acc[0][0] = zero; acc[0][1] = zero; acc[1][0] = zero; acc[1][1] = zero;
  float ss0 = 0.f, ss1 = 0.f;

  const float* a0 = hs + (size_t)(row0 + r16) * HD_DIM + kbase;
  const float* a1 = a0 + (size_t)16 * HD_DIM;
  const unsigned short* b0p = fnb + (size_t)r16 * HD_DIM + kbase;
  const unsigned short* b1p = b0p + (size_t)16 * HD_DIM;
  unsigned short* h0 = hsb + (size_t)(row0 + r16) * HD_DIM + kbase;

#pragma unroll 4
  for (int kk = 0; kk < 256; kk += 32) {
    const f32x4 va0 = *(const f32x4*)(a0 + kk);
    const f32x4 va0b = *(const f32x4*)(a0 + kk + 4);
    const f32x4 va1 = *(const f32x4*)(a1 + kk);
    const f32x4 va1b = *(const f32x4*)(a1 + kk + 4);
    const bf16x8 fb0 = *(const bf16x8*)(b0p + kk);
    const bf16x8 fb1 = *(const bf16x8*)(b1p + kk);
    ss0 += va0.x * va0.x + va0.y * va0.y + va0.z * va0.z + va0.w * va0.w
         + va0b.x * va0b.x + va0b.y * va0b.y + va0b.z * va0b.z + va0b.w * va0b.w;
    ss1 += va1.x * va1.x + va1.y * va1.y + va1.z * va1.z + va1.w * va1.w
         + va1b.x * va1b.x + va1b.y * va1b.y + va1b.z * va1b.z + va1b.w * va1b.w;
    bf16x8 fa0, fa1;
    fa0[0] = (__bf16)va0.x; fa0[1] = (__bf16)va0.y; fa0[2] = (__bf16)va0.z; fa0[3] = (__bf16)va0.w;
    fa0[4] = (__bf16)va0b.x; fa0[5] = (__bf16)va0b.y; fa0[6] = (__bf16)va0b.z; fa0[7] = (__bf16)va0b.w;
    fa1[0] = (__bf16)va1.x; fa1[1] = (__bf16)va1.y; fa1[2] = (__bf16)va1.z; fa1[3] = (__bf16)va1.w;
    fa1[4] = (__bf16)va1b.x; fa1[5] = (__bf16)va1b.y; fa1[6] = (__bf16)va1b.z; fa1[7] = (__bf16)va1b.w;
    if (WH) {
      *(bf16x8*)(h0 + kk) = fa0;
      *(bf16x8*)(h0 + (size_t)16 * HD_DIM + kk) = fa1;
    }
    acc[0][0] = __builtin_amdgcn_mfma_f32_16x16x32_bf16(fa0, fb0, acc[0][0], 0, 0, 0);
    acc[0][1] = __builtin_amdgcn_mfma_f32_16x16x32_bf16(fa0, fb1, acc[0][1], 0, 0, 0);
    acc[1][0] = __builtin_amdgcn_mfma_f32_16x16x32_bf16(fa1, fb0, acc[1][0], 0, 0, 0);
    acc[1][1] = __builtin_amdgcn_mfma_f32_16x16x32_bf16(fa1, fb1, acc[1][1], 0, 0, 0);
  }

  // sumsq: combine the 4 kq lanes sharing (lane&15)
  ss0 += __shfl_xor(ss0, 16, 64); ss0 += __shfl_xor(ss0, 32, 64);
  ss1 += __shfl_xor(ss1, 16, 64); ss1 += __shfl_xor(ss1, 32, 64);
  if (lane < 16) {
    sumsqpart[(size_t)p * S_DIM + row0 + lane] = ss0;
    sumsqpart[(size_t)p * S_DIM + row0 + 16 + lane] = ss1;
  }

  // C write: row = row0 + mi*16 + (lane>>4)*4 + j, col = ni*16 + (lane&15)
  const int cr = (lane >> 4) * 4, cc = lane & 15;
#pragma unroll
  for (int mi = 0; mi < 2; mi++)
#pragma unroll
    for (int ni = 0; ni < 2; ni++) {
      const int col = ni * 16 + cc;
      if (col < MIXN) {
#pragma unroll
        for (int j = 0; j < 4; j++) {
          const int row = row0 + mi * 16 + cr + j;
          mixpart[((size_t)p * S_DIM + row) * MIXN + col] = acc[mi][ni][j];
        }
      }
    }
}

// ---------------------------------------------------------------------------
// K2: sum the 64 K-split partials (4-way p-split per row, LDS combine) then
// sigmoid + 20-iter Sinkhorn. 64 blocks -> 64 CUs streaming the 26MB.
__global__ __launch_bounds__(256) void k_gates(const float* __restrict__ mixpart,
                                               const float* __restrict__ sumsqpart,
                                               const float* __restrict__ hbase,
                                               const float* __restrict__ hscale,
                                               float* __restrict__ gates) {
  __shared__ float sm[4][64][25];
  const int t = threadIdx.x, rl = t & 63, pq = t >> 6;
  const int row = blockIdx.x * 64 + rl;
  float mr[MIXN];
#pragma unroll
  for (int m = 0; m < MIXN; m++) mr[m] = 0.f;
  float ss = 0.f;
  for (int p = pq * 16; p < pq * 16 + 16; p++) {
    const float* mp = mixpart + ((size_t)p * S_DIM + row) * MIXN;
#pragma unroll
    for (int m = 0; m < MIXN; m++) mr[m] += mp[m];
    ss += sumsqpart[(size_t)p * S_DIM + row];
  }
#pragma unroll
  for (int m = 0; m < MIXN; m++) sm[pq][rl][m] = mr[m];
  sm[pq][rl][24] = ss;
  __syncthreads();

  if (t < 64) {
    const int r2 = blockIdx.x * 64 + t;
    float g[MIXN], sumsq = sm[0][t][24] + sm[1][t][24] + sm[2][t][24] + sm[3][t][24];
    const float rs = rsqrtf(sumsq * (1.0f / HD_DIM) + 1e-6f);
    const float ps = hscale[0], qs = hscale[1], cs = hscale[2];
#pragma unroll
    for (int m = 0; m < MIXN; m++) {
      const float mv = sm[0][t][m] + sm[1][t][m] + sm[2][t][m] + sm[3][t][m];
      const float sc = (m < 4) ? ps : ((m < 8) ? qs : cs);
      const float x = mv * rs * sc + hbase[m];
      g[m] = 1.0f / (1.0f + expf(-x)) + 1e-6f;
    }
    for (int it = 0; it < SINK_IT; it++) {
#pragma unroll
      for (int i = 0; i < 4; i++) {
        const float s = g[8 + i * 4 + 0] + g[8 + i * 4 + 1] + g[8 + i * 4 + 2] + g[8 + i * 4 + 3] + 1e-6f;
#pragma unroll
        for (int j = 0; j < 4; j++) g[8 + i * 4 + j] /= s;
      }
#pragma unroll
      for (int j = 0; j < 4; j++) {
        const float s = g[8 + 0 + j] + g[8 + 4 + j] + g[8 + 8 + j] + g[8 + 12 + j] + 1e-6f;
#pragma unroll
        for (int i = 0; i < 4; i++) g[8 + i * 4 + j] /= s;
      }
    }
    float* go = gates + (size_t)r2 * MIXN;
#pragma unroll
    for (int m = 0; m < MIXN; m++) go[m] = g[m];
  }
}

// ---------------------------------------------------------------------------
// K3 (fp32 fallback): reduced = pre.hs -> RMSNorm -> normed (bf16)
__global__ __launch_bounds__(256) void k_reduce_norm(const float* __restrict__ hs,
                                                     const float* __restrict__ gates,
                                                     const float* __restrict__ nw,
                                                     unsigned short* __restrict__ normed) {
  const int s = blockIdx.x, tid = threadIdx.x;
  const int lane = tid & 63, wave = tid >> 6;
  const float* g = gates + (size_t)s * MIXN;
  const float p0 = g[0], p1 = g[1], p2 = g[2], p3 = g[3];
  const size_t base = (size_t)s * HC_N * H_DIM;

  f32x4 red[4];
  float ssq = 0.f;
#pragma unroll
  for (int it = 0; it < 4; ++it) {
    const int d4 = it * 256 + tid;
    f32x4 a = *(const f32x4*)(hs + base + (size_t)0 * H_DIM + (size_t)d4 * 4);
    f32x4 b = *(const f32x4*)(hs + base + (size_t)1 * H_DIM + (size_t)d4 * 4);
    f32x4 c = *(const f32x4*)(hs + base + (size_t)2 * H_DIM + (size_t)d4 * 4);
    f32x4 d = *(const f32x4*)(hs + base + (size_t)3 * H_DIM + (size_t)d4 * 4);
    f32x4 v = p0 * a + p1 * b + p2 * c + p3 * d;
    red[it] = v;
    ssq += v.x * v.x + v.y * v.y + v.z * v.z + v.w * v.w;
  }
#pragma unroll
  for (int off = 32; off >= 1; off >>= 1) ssq += __shfl_xor(ssq, off, 64);
  __shared__ float ls[4];
  if (lane == 0) ls[wave] = ssq;
  __syncthreads();
  const float tot = ls[0] + ls[1] + ls[2] + ls[3];
  const float nr = rsqrtf(tot * (1.0f / H_DIM) + 1e-6f);
#pragma unroll
  for (int it = 0; it < 4; ++it) {
    const int d4 = it * 256 + tid;
    f32x4 w = *(const f32x4*)(nw + (size_t)d4 * 4);
    f32x4 v = red[it] * nr;
    v = v * w;
    u16x4 o;
    o[0] = f2bf(v.x); o[1] = f2bf(v.y); o[2] = f2bf(v.z); o[3] = f2bf(v.w);
    *(u16x4*)(normed + (size_t)s * H_DIM + (size_t)d4 * 4) = o;
  }
}

// K3b (big-ws): same but reads the bf16 hs copy (halves read traffic)
__global__ __launch_bounds__(256) void k_rn_bf(const unsigned short* __restrict__ hsb,
                                               const float* __restrict__ gates,
                                               const float* __restrict__ nw,
                                               unsigned short* __restrict__ normed) {
  const int s = blockIdx.x, tid = threadIdx.x;
  const int lane = tid & 63, wave = tid >> 6;
  const float* g = gates + (size_t)s * MIXN;
  const float p0 = g[0], p1 = g[1], p2 = g[2], p3 = g[3];
  const size_t base = (size_t)s * HC_N * H_DIM;

  float red[16];
  float ssq = 0.f;
#pragma unroll
  for (int it = 0; it < 2; ++it) {
    const int d8 = (it * 256 + tid) * 8;
    const u16x8 a = *(const u16x8*)(hsb + base + 0 * H_DIM + d8);
    const u16x8 b = *(const u16x8*)(hsb + base + 1 * H_DIM + d8);
    const u16x8 c = *(const u16x8*)(hsb + base + 2 * H_DIM + d8);
    const u16x8 d = *(const u16x8*)(hsb + base + 3 * H_DIM + d8);
#pragma unroll
    for (int k = 0; k < 8; ++k) {
      const float v = p0 * bf2f(a[k]) + p1 * bf2f(b[k]) + p2 * bf2f(c[k]) + p3 * bf2f(d[k]);
      red[it * 8 + k] = v;
      ssq += v * v;
    }
  }
#pragma unroll
  for (int off = 32; off >= 1; off >>= 1) ssq += __shfl_xor(ssq, off, 64);
  __shared__ float ls[4];
  if (lane == 0) ls[wave] = ssq;
  __syncthreads();
  const float tot = ls[0] + ls[1] + ls[2] + ls[3];
  const float nr = rsqrtf(tot * (1.0f / H_DIM) + 1e-6f);
#pragma unroll
  for (int it = 0; it < 2; ++it) {
    const int d8 = (it * 256 + tid) * 8;
    const f32x4 w0 = *(const f32x4*)(nw + d8);
    const f32x4 w1 = *(const f32x4*)(nw + d8 + 4);
    u16x8 o;
    o[0] = f2bf(red[it * 8 + 0] * nr * w0.x); o[1] = f2bf(red[it * 8 + 1] * nr * w0.y);
    o[2] = f2bf(red[it * 8 + 2] * nr * w0.z); o[3] = f2bf(red[it * 8 + 3] * nr * w0.w);
    o[4] = f2bf(red[it * 8 + 4] * nr * w1.x); o[5] = f2bf(red[it * 8 + 5] * nr * w1.y);
    o[6] = f2bf(red[it * 8 + 6] * nr * w1.z); o[7] = f2bf(red[it * 8 + 7] * nr * w1.w);
    *(u16x8*)(normed + (size_t)s * H_DIM + d8) = o;
  }
}

// ---------------------------------------------------------------------------
// K4: bf16 GEMM (FROZEN, R11 win): m97-class 128x128 2-barrier BK=32,
// 4 blocks/CU, zero-conflict quad swizzle. 172-177us, ~797 TF.
__device__ __forceinline__ void gload_lds16(const unsigned short* g, unsigned short* l) {
  __builtin_amdgcn_global_load_lds(
      (const __attribute__((address_space(1))) unsigned int*)(const void*)g,
      (__attribute__((address_space(3))) unsigned int*)(void*)l, 16, 0, 0);
}

__global__ __launch_bounds__(256, 4) void k_gemm(const unsigned short* __restrict__ A,
                                                 const unsigned short* __restrict__ B,
                                                 unsigned short* __restrict__ C) {
  __shared__ __align__(16) unsigned short sA[128 * 32];
  __shared__ __align__(16) unsigned short sB[128 * 32];
  const int tid = threadIdx.x;
  const int lane = tid & 63, wave = tid >> 6;
  const int bm = blockIdx.y, bn = blockIdx.x;
  const int wm = wave >> 1, wn = wave & 1;

  f32x4 zero = {0.f, 0.f, 0.f, 0.f};
  f32x4 acc[4][4];
#pragma unroll
  for (int mi = 0; mi < 4; mi++)
#pragma unroll
    for (int ni = 0; ni < 4; ni++) acc[mi][ni] = zero;

  const int strow = lane >> 2;          // 0..15
  const int stk = (((lane & 3) ^ ((lane >> 3) & 3)) * 8);  // swizzled src k-off
  const unsigned short* ga = A + (size_t)(bm * 128) * 4096;
  const unsigned short* gb = B + (size_t)(bn * 128) * 4096;
  const int c0 = wave * 2, c1 = wave * 2 + 1;

  const int rb = lane & 15;
  const int fk = (((lane >> 4) ^ ((lane >> 1) & 3)) * 8);

  for (int kk = 0; kk < 4096; kk += 32) {
    gload_lds16(ga + (size_t)(c0 * 16 + strow) * 4096 + kk + stk, sA + c0 * 512);
    gload_lds16(ga + (size_t)(c1 * 16 + strow) * 4096 + kk + stk, sA + c1 * 512);
    gload_lds16(gb + (size_t)(c0 * 16 + strow) * 4096 + kk + stk, sB + c0 * 512);
    gload_lds16(gb + (size_t)(c1 * 16 + strow) * 4096 + kk + stk, sB + c1 * 512);
    __syncthreads();

    bf16x8 af[4], bfr[4];
#pragma unroll
    for (int mi = 0; mi < 4; mi++)
      af[mi] = *(const bf16x8*)(sA + (wm * 64 + mi * 16 + rb) * 32 + fk);
#pragma unroll
    for (int ni = 0; ni < 4; ni++)
      bfr[ni] = *(const bf16x8*)(sB + (wn * 64 + ni * 16 + rb) * 32 + fk);
#pragma unroll
    for (int mi = 0; mi < 4; mi++)
#pragma unroll
      for (int ni = 0; ni < 4; ni++)
        acc[mi][ni] = __builtin_amdgcn_mfma_f32_16x16x32_bf16(af[mi], bfr[ni], acc[mi][ni], 0, 0, 0);
    __syncthreads();
  }

  const int cr = (lane >> 4) * 4, cc = lane & 15;
#pragma unroll
  for (int mi = 0; mi < 4; mi++)
#pragma unroll
    for (int ni = 0; ni < 4; ni++)
#pragma unroll
      for (int j = 0; j < 4; j++) {
        const int row = bm * 128 + wm * 64 + mi * 16 + cr + j;
        const int col = bn * 128 + wn * 64 + ni * 16 + cc;
        C[(size_t)row * 4096 + col] = f2bf(acc[mi][ni][j]);
      }
}

// ---------------------------------------------------------------------------
// K5 (fp32 fallback): expanded = post*out + comb@hs
__global__ __launch_bounds__(256) void k_expand(const float* __restrict__ hs,
                                                const unsigned short* __restrict__ outb,
                                                const float* __restrict__ gates,
                                                float* __restrict__ y) {
  const int s = blockIdx.x, tid = threadIdx.x;
  const float* g = gates + (size_t)s * MIXN;
  float post[4], cb[4][4];
#pragma unroll
  for (int h = 0; h < 4; h++) post[h] = g[4 + h];
#pragma unroll
  for (int h = 0; h < 4; h++)
#pragma unroll
    for (int k = 0; k < 4; k++) cb[h][k] = g[8 + h * 4 + k];

  const size_t base = (size_t)s * HC_N * H_DIM;
#pragma unroll
  for (int it = 0; it < 4; ++it) {
    const int d4 = it * 256 + tid;
    f32x4 hv[4];
#pragma unroll
    for (int k = 0; k < 4; k++)
      hv[k] = *(const f32x4*)(hs + base + (size_t)k * H_DIM + (size_t)d4 * 4);
    u16x4 ob = *(const u16x4*)(outb + (size_t)s * H_DIM + (size_t)d4 * 4);
    f32x4 o = {bf2f(ob[0]), bf2f(ob[1]), bf2f(ob[2]), bf2f(ob[3])};
#pragma unroll
    for (int h = 0; h < 4; h++) {
      f32x4 e = post[h] * o + cb[h][0] * hv[0] + cb[h][1] * hv[1] + cb[h][2] * hv[2] + cb[h][3] * hv[3];
      *(f32x4*)(y + base + (size_t)h * H_DIM + (size_t)d4 * 4) = e;
    }
  }
}

// K5b (big-ws): reads the bf16 hs copy (read traffic 288->160MB)
__global__ __launch_bounds__(256) void k_expand_bf(const unsigned short* __restrict__ hsb,
                                                   const unsigned short* __restrict__ outb,
                                                   const float* __restrict__ gates,
                                                   float* __restrict__ y) {
  const int s = blockIdx.x, tid = threadIdx.x;
  const float* g = gates + (size_t)s * MIXN;
  float post[4], cb[4][4];
#pragma unroll
  for (int h = 0; h < 4; h++) post[h] = g[4 + h];
#pragma unroll
  for (int h = 0; h < 4; h++)
#pragma unroll
    for (int k = 0; k < 4; k++) cb[h][k] = g[8 + h * 4 + k];

  const size_t base = (size_t)s * HC_N * H_DIM;
#pragma unroll
  for (int it = 0; it < 2; ++it) {
    const int d8 = (it * 256 + tid) * 8;
    const u16x8 a = *(const u16x8*)(hsb + base + 0 * H_DIM + d8);
    const u16x8 b = *(const u16x8*)(hsb + base + 1 * H_DIM + d8);
    const u16x8 c = *(const u16x8*)(hsb + base + 2 * H_DIM + d8);
    const u16x8 d = *(const u16x8*)(hsb + base + 3 * H_DIM + d8);
    const u16x8 ob = *(const u16x8*)(outb + (size_t)s * H_DIM + d8);
#pragma unroll
    for (int h = 0; h < 4; h++) {
      float e[8];
#pragma unroll
      for (int k = 0; k < 8; ++k)
        e[k] = post[h] * bf2f(ob[k]) + cb[h][0] * bf2f(a[k]) + cb[h][1] * bf2f(b[k])
             + cb[h][2] * bf2f(c[k]) + cb[h][3] * bf2f(d[k]);
      f32x4 e0 = {e[0], e[1], e[2], e[3]};
      f32x4 e1 = {e[4], e[5], e[6], e[7]};
      *(f32x4*)(y + base + (size_t)h * H_DIM + d8) = e0;
      *(f32x4*)(y + base + (size_t)h * H_DIM + d8 + 4) = e1;
    }
  }
}

// ---------------------------------------------------------------------------
extern "C" void kernel_launch(void* const* d_in, const int* in_sizes, int n_in,
                              void* d_out, int out_size, void* d_ws, size_t ws_size,
                              hipStream_t stream) {
  const float* hs = (const float*)d_in[0];      // [1,4096,4,4096]
  const float* fn = (const float*)d_in[1];      // [24,16384]
  const float* hbase = (const float*)d_in[2];   // [24]
  const float* hscale = (const float*)d_in[3];  // [3]
  const float* nw = (const float*)d_in[4];      // [4096]
  const float* wi = (const float*)d_in[5];      // [4096,4096]
  float* y = (float*)d_out;                     // [1,4096,4,4096] fp32

  // Layout (bytes). normed overlays mixpart+fnb (dead after k_gates).
  char* ws = (char*)d_ws;
  float* gates = (float*)(ws);                                  // [0, 0.5MB)
  float* sumsqpart = (float*)(ws + 524288);                     // [0.5, 1.5MB) 4096*64*4
  float* mixpart = (float*)(ws + 2097152);                      // [2, 27.2MB) 4096*64*24*4
  unsigned short* fnb = (unsigned short*)(ws + 29360128);       // [28, 29MB)
  unsigned short* normed = (unsigned short*)(ws + 2097152);     // [2, 34MB) overlays mixpart/fnb
  unsigned short* wb = (unsigned short*)(ws + 37748736);        // [36, 68MB)
  unsigned short* outb = (unsigned short*)(ws + 71303168);      // [68, 100MB)
  unsigned short* hsb = (unsigned short*)(ws + 104857600);      // [100, 228MB) big path only
  const bool big = ws_size >= (size_t)104857600 + 134217728;    // 228MB needed

  k_w2bf<<<8448, 256, 0, stream>>>(wi, wb, fn, fnb);
  if (big)
    k_mixgemm<true><<<dim3(32, KSPL), 256, 0, stream>>>(hs, fnb, mixpart, sumsqpart, hsb);
  else
    k_mixgemm<false><<<dim3(32, KSPL), 256, 0, stream>>>(hs, fnb, mixpart, sumsqpart, hsb);
  k_gates<<<64, 256, 0, stream>>>(mixpart, sumsqpart, hbase, hscale, gates);
  if (big)
    k_rn_bf<<<4096, 256, 0, stream>>>(hsb, gates, nw, normed);
  else
    k_reduce_norm<<<4096, 256, 0, stream>>>(hs, gates, nw, normed);
  k_gemm<<<dim3(32, 32), 256, 0, stream>>>(normed, wb, outb);
  if (big)
    k_expand_bf<<<4096, 256, 0, stream>>>(hsb, outb, gates, y);
  else
    k_expand<<<4096, 256, 0, stream>>>(hs, outb, gates, y);
}

// Round 14
// 434.799 us; speedup vs baseline: 1.0129x; 1.0129x over previous
//
#include <hip/hip_runtime.h>
#include <math.h>

// Problem dims (fixed by the reference)
#define S_DIM 4096
#define H_DIM 4096
#define HC_N 4
#define HD_DIM 16384   // HC_N * H_DIM
#define MIXN 24        // (2+HC)*HC
#define SINK_IT 20
#define KSPL 32        // K-split for mixgemm (512 k per slice)

typedef float f32x4 __attribute__((ext_vector_type(4)));
typedef __bf16 bf16x8 __attribute__((ext_vector_type(8)));
typedef unsigned short u16x8 __attribute__((ext_vector_type(8)));
typedef unsigned short u16x4 __attribute__((ext_vector_type(4)));

__device__ __forceinline__ unsigned short f2bf(float f) {
  unsigned u = __builtin_bit_cast(unsigned, f);
  u += 0x7FFFu + ((u >> 16) & 1u);   // round-to-nearest-even
  return (unsigned short)(u >> 16);
}
__device__ __forceinline__ float bf2f(unsigned short h) {
  return __builtin_bit_cast(float, (unsigned)h << 16);
}

// ---------------------------------------------------------------------------
// K0: fp32->bf16 conversions: w_inner (blocks 0..8191), hc_fn (8192..8383),
// fnb zero-pad rows 24..31 (8384..8447).
__global__ __launch_bounds__(256) void k_w2bf(const float* __restrict__ w,
                                              unsigned short* __restrict__ wb,
                                              const float* __restrict__ fn,
                                              unsigned short* __restrict__ fnb) {
  const int b = blockIdx.x;
  if (b < 8192) {
    const size_t i = (size_t)b * 2048 + threadIdx.x * 8;
    f32x4 a = *(const f32x4*)(w + i);
    f32x4 c = *(const f32x4*)(w + i + 4);
    u16x8 o;
    o[0] = f2bf(a.x); o[1] = f2bf(a.y); o[2] = f2bf(a.z); o[3] = f2bf(a.w);
    o[4] = f2bf(c.x); o[5] = f2bf(c.y); o[6] = f2bf(c.z); o[7] = f2bf(c.w);
    *(u16x8*)(wb + i) = o;
  } else if (b < 8384) {
    const size_t i = (size_t)(b - 8192) * 2048 + threadIdx.x * 8;  // < 393216
    f32x4 a = *(const f32x4*)(fn + i);
    f32x4 c = *(const f32x4*)(fn + i + 4);
    u16x8 o;
    o[0] = f2bf(a.x); o[1] = f2bf(a.y); o[2] = f2bf(a.z); o[3] = f2bf(a.w);
    o[4] = f2bf(c.x); o[5] = f2bf(c.y); o[6] = f2bf(c.z); o[7] = f2bf(c.w);
    *(u16x8*)(fnb + i) = o;
  } else {
    const size_t i = 393216 + (size_t)(b - 8384) * 2048 + threadIdx.x * 8;
    u16x8 o = {0, 0, 0, 0, 0, 0, 0, 0};
    *(u16x8*)(fnb + i) = o;
  }
}

// ---------------------------------------------------------------------------
// K1: mixes as MFMA GEMM: mixpart[row][p][24] += hs[row,:] . fnb[m,:] over
// the p-th K-slice (512 k). hs read fp32 directly from global (each element
// exactly once chip-wide), converted in-register to bf16; fp32 sumsq from
// the SAME loads pre-conversion -> sumsqpart[row][p]. 1024 blocks (4/CU).
// Fragment + C layouts mirror the refcheck-passing k_gemm. Deterministic
// (K-split partials, no atomics); k_gates sums the 32 partials.
__global__ __launch_bounds__(256) void k_mixgemm(const float* __restrict__ hs,
                                                 const unsigned short* __restrict__ fnb,
                                                 float* __restrict__ mixpart,
                                                 float* __restrict__ sumsqpart) {
  const int rt = blockIdx.x;    // row tile: 128 rows
  const int p = blockIdx.y;     // k slice: 512 k
  const int tid = threadIdx.x, lane = tid & 63, wave = tid >> 6;
  const int r16 = lane & 15, kq = lane >> 4;
  const int row0 = rt * 128 + wave * 32;
  const size_t kbase = (size_t)p * 512 + kq * 8;

  f32x4 acc[2][2];
  f32x4 zero = {0.f, 0.f, 0.f, 0.f};
  acc[0][0] = zero; acc[0][1] = zero; acc[1][0] = zero; acc[1][1] = zero;
  float ss0 = 0.f, ss1 = 0.f;

  const float* a0 = hs + (size_t)(row0 + r16) * HD_DIM + kbase;
  const float* a1 = hs + (size_t)(row0 + 16 + r16) * HD_DIM + kbase;
  const unsigned short* b0p = fnb + (size_t)r16 * HD_DIM + kbase;
  const unsigned short* b1p = fnb + (size_t)(16 + r16) * HD_DIM + kbase;

#pragma unroll 4
  for (int kk = 0; kk < 512; kk += 32) {
    const f32x4 va0 = *(const f32x4*)(a0 + kk);
    const f32x4 va0b = *(const f32x4*)(a0 + kk + 4);
    const f32x4 va1 = *(const f32x4*)(a1 + kk);
    const f32x4 va1b = *(const f32x4*)(a1 + kk + 4);
    const bf16x8 fb0 = *(const bf16x8*)(b0p + kk);
    const bf16x8 fb1 = *(const bf16x8*)(b1p + kk);
    ss0 += va0.x * va0.x + va0.y * va0.y + va0.z * va0.z + va0.w * va0.w
         + va0b.x * va0b.x + va0b.y * va0b.y + va0b.z * va0b.z + va0b.w * va0b.w;
    ss1 += va1.x * va1.x + va1.y * va1.y + va1.z * va1.z + va1.w * va1.w
         + va1b.x * va1b.x + va1b.y * va1b.y + va1b.z * va1b.z + va1b.w * va1b.w;
    bf16x8 fa0, fa1;
    fa0[0] = (__bf16)va0.x; fa0[1] = (__bf16)va0.y; fa0[2] = (__bf16)va0.z; fa0[3] = (__bf16)va0.w;
    fa0[4] = (__bf16)va0b.x; fa0[5] = (__bf16)va0b.y; fa0[6] = (__bf16)va0b.z; fa0[7] = (__bf16)va0b.w;
    fa1[0] = (__bf16)va1.x; fa1[1] = (__bf16)va1.y; fa1[2] = (__bf16)va1.z; fa1[3] = (__bf16)va1.w;
    fa1[4] = (__bf16)va1b.x; fa1[5] = (__bf16)va1b.y; fa1[6] = (__bf16)va1b.z; fa1[7] = (__bf16)va1b.w;
    acc[0][0] = __builtin_amdgcn_mfma_f32_16x16x32_bf16(fa0, fb0, acc[0][0], 0, 0, 0);
    acc[0][1] = __builtin_amdgcn_mfma_f32_16x16x32_bf16(fa0, fb1, acc[0][1], 0, 0, 0);
    acc[1][0] = __builtin_amdgcn_mfma_f32_16x16x32_bf16(fa1, fb0, acc[1][0], 0, 0, 0);
    acc[1][1] = __builtin_amdgcn_mfma_f32_16x16x32_bf16(fa1, fb1, acc[1][1], 0, 0, 0);
  }

  // sumsq: combine lanes sharing (lane&15) -> rows row0+r16, row0+16+r16
  ss0 += __shfl_xor(ss0, 16, 64); ss0 += __shfl_xor(ss0, 32, 64);
  ss1 += __shfl_xor(ss1, 16, 64); ss1 += __shfl_xor(ss1, 32, 64);
  if (lane < 16) {
    sumsqpart[(size_t)(row0 + lane) * KSPL + p] = ss0;
    sumsqpart[(size_t)(row0 + 16 + lane) * KSPL + p] = ss1;
  }

  // C write: row = row0 + mi*16 + (lane>>4)*4 + j, col = ni*16 + (lane&15)
  const int cr = (lane >> 4) * 4, cc = lane & 15;
#pragma unroll
  for (int mi = 0; mi < 2; mi++)
#pragma unroll
    for (int ni = 0; ni < 2; ni++) {
      const int col = ni * 16 + cc;
      if (col < MIXN) {
#pragma unroll
        for (int j = 0; j < 4; j++) {
          const int row = row0 + mi * 16 + cr + j;
          mixpart[((size_t)row * KSPL + p) * MIXN + col] = acc[mi][ni][j];
        }
      }
    }
}

// ---------------------------------------------------------------------------
// K2: gates: sum the K-split partials, sigmoid + 20-iter Sinkhorn per row
__global__ __launch_bounds__(256) void k_gates(const float* __restrict__ mixpart,
                                               const float* __restrict__ sumsqpart,
                                               const float* __restrict__ hbase,
                                               const float* __restrict__ hscale,
                                               float* __restrict__ gates) {
  const int row = blockIdx.x * 256 + threadIdx.x;
  float sumsq = 0.f;
  const float* sp = sumsqpart + (size_t)row * KSPL;
#pragma unroll
  for (int p = 0; p < KSPL; p++) sumsq += sp[p];
  float mr[MIXN];
#pragma unroll
  for (int m = 0; m < MIXN; m++) mr[m] = 0.f;
  const float* mp = mixpart + (size_t)row * KSPL * MIXN;
  for (int p = 0; p < KSPL; p++) {
#pragma unroll
    for (int m = 0; m < MIXN; m++) mr[m] += mp[p * MIXN + m];
  }
  const float rs = rsqrtf(sumsq * (1.0f / HD_DIM) + 1e-6f);
  const float ps = hscale[0], qs = hscale[1], cs = hscale[2];
  float g[MIXN];
#pragma unroll
  for (int m = 0; m < MIXN; m++) {
    const float sc = (m < 4) ? ps : ((m < 8) ? qs : cs);
    const float x = mr[m] * rs * sc + hbase[m];
    g[m] = 1.0f / (1.0f + expf(-x)) + 1e-6f;
  }
  for (int t = 0; t < SINK_IT; t++) {
#pragma unroll
    for (int i = 0; i < 4; i++) {
      const float s = g[8 + i * 4 + 0] + g[8 + i * 4 + 1] + g[8 + i * 4 + 2] + g[8 + i * 4 + 3] + 1e-6f;
#pragma unroll
      for (int j = 0; j < 4; j++) g[8 + i * 4 + j] /= s;
    }
#pragma unroll
    for (int j = 0; j < 4; j++) {
      const float s = g[8 + 0 + j] + g[8 + 4 + j] + g[8 + 8 + j] + g[8 + 12 + j] + 1e-6f;
#pragma unroll
      for (int i = 0; i < 4; i++) g[8 + i * 4 + j] /= s;
    }
  }
  float* go = gates + (size_t)row * MIXN;
#pragma unroll
  for (int m = 0; m < MIXN; m++) go[m] = g[m];
}

// ---------------------------------------------------------------------------
// K3: reduced = pre . hs  -> RMSNorm -> normed (bf16).  One block per row s.
__global__ __launch_bounds__(256) void k_reduce_norm(const float* __restrict__ hs,
                                                     const float* __restrict__ gates,
                                                     const float* __restrict__ nw,
                                                     unsigned short* __restrict__ normed) {
  const int s = blockIdx.x, tid = threadIdx.x;
  const int lane = tid & 63, wave = tid >> 6;
  const float* g = gates + (size_t)s * MIXN;
  const float p0 = g[0], p1 = g[1], p2 = g[2], p3 = g[3];
  const size_t base = (size_t)s * HC_N * H_DIM;

  f32x4 red[4];
  float ssq = 0.f;
#pragma unroll
  for (int it = 0; it < 4; ++it) {
    const int d4 = it * 256 + tid;
    f32x4 a = *(const f32x4*)(hs + base + (size_t)0 * H_DIM + (size_t)d4 * 4);
    f32x4 b = *(const f32x4*)(hs + base + (size_t)1 * H_DIM + (size_t)d4 * 4);
    f32x4 c = *(const f32x4*)(hs + base + (size_t)2 * H_DIM + (size_t)d4 * 4);
    f32x4 d = *(const f32x4*)(hs + base + (size_t)3 * H_DIM + (size_t)d4 * 4);
    f32x4 v = p0 * a + p1 * b + p2 * c + p3 * d;
    red[it] = v;
    ssq += v.x * v.x + v.y * v.y + v.z * v.z + v.w * v.w;
  }
#pragma unroll
  for (int off = 32; off >= 1; off >>= 1) ssq += __shfl_xor(ssq, off, 64);
  __shared__ float ls[4];
  if (lane == 0) ls[wave] = ssq;
  __syncthreads();
  const float tot = ls[0] + ls[1] + ls[2] + ls[3];
  const float nr = rsqrtf(tot * (1.0f / H_DIM) + 1e-6f);
#pragma unroll
  for (int it = 0; it < 4; ++it) {
    const int d4 = it * 256 + tid;
    f32x4 w = *(const f32x4*)(nw + (size_t)d4 * 4);
    f32x4 v = red[it] * nr;
    v = v * w;
    u16x4 o;
    o[0] = f2bf(v.x); o[1] = f2bf(v.y); o[2] = f2bf(v.z); o[3] = f2bf(v.w);
    *(u16x4*)(normed + (size_t)s * H_DIM + (size_t)d4 * 4) = o;
  }
}

// ---------------------------------------------------------------------------
// K4: bf16 GEMM  C[s][e] = sum_d A[s][d] * B[e][d]
// FROZEN (R11 win): m97-class 128x128 2-barrier single-buffered BK=32,
// multi-block/CU (4 pinned), zero-conflict quad swizzle. 172us, 797 TF.
__device__ __forceinline__ void gload_lds16(const unsigned short* g, unsigned short* l) {
  __builtin_amdgcn_global_load_lds(
      (const __attribute__((address_space(1))) unsigned int*)(const void*)g,
      (__attribute__((address_space(3))) unsigned int*)(void*)l, 16, 0, 0);
}

__global__ __launch_bounds__(256, 4) void k_gemm(const unsigned short* __restrict__ A,
                                                 const unsigned short* __restrict__ B,
                                                 unsigned short* __restrict__ C) {
  __shared__ __align__(16) unsigned short sA[128 * 32];
  __shared__ __align__(16) unsigned short sB[128 * 32];
  const int tid = threadIdx.x;
  const int lane = tid & 63, wave = tid >> 6;
  const int bm = blockIdx.y, bn = blockIdx.x;
  const int wm = wave >> 1, wn = wave & 1;

  f32x4 zero = {0.f, 0.f, 0.f, 0.f};
  f32x4 acc[4][4];
#pragma unroll
  for (int mi = 0; mi < 4; mi++)
#pragma unroll
    for (int ni = 0; ni < 4; ni++) acc[mi][ni] = zero;

  const int strow = lane >> 2;          // 0..15
  const int stk = (((lane & 3) ^ ((lane >> 3) & 3)) * 8);  // swizzled src k-off
  const unsigned short* ga = A + (size_t)(bm * 128) * 4096;
  const unsigned short* gb = B + (size_t)(bn * 128) * 4096;
  const int c0 = wave * 2, c1 = wave * 2 + 1;

  const int rb = lane & 15;
  const int fk = (((lane >> 4) ^ ((lane >> 1) & 3)) * 8);

  for (int kk = 0; kk < 4096; kk += 32) {
    gload_lds16(ga + (size_t)(c0 * 16 + strow) * 4096 + kk + stk, sA + c0 * 512);
    gload_lds16(ga + (size_t)(c1 * 16 + strow) * 4096 + kk + stk, sA + c1 * 512);
    gload_lds16(gb + (size_t)(c0 * 16 + strow) * 4096 + kk + stk, sB + c0 * 512);
    gload_lds16(gb + (size_t)(c1 * 16 + strow) * 4096 + kk + stk, sB + c1 * 512);
    __syncthreads();

    bf16x8 af[4], bfr[4];
#pragma unroll
    for (int mi = 0; mi < 4; mi++)
      af[mi] = *(const bf16x8*)(sA + (wm * 64 + mi * 16 + rb) * 32 + fk);
#pragma unroll
    for (int ni = 0; ni < 4; ni++)
      bfr[ni] = *(const bf16x8*)(sB + (wn * 64 + ni * 16 + rb) * 32 + fk);
#pragma unroll
    for (int mi = 0; mi < 4; mi++)
#pragma unroll
      for (int ni = 0; ni < 4; ni++)
        acc[mi][ni] = __builtin_amdgcn_mfma_f32_16x16x32_bf16(af[mi], bfr[ni], acc[mi][ni], 0, 0, 0);
    __syncthreads();
  }

  const int cr = (lane >> 4) * 4, cc = lane & 15;
#pragma unroll
  for (int mi = 0; mi < 4; mi++)
#pragma unroll
    for (int ni = 0; ni < 4; ni++)
#pragma unroll
      for (int j = 0; j < 4; j++) {
        const int row = bm * 128 + wm * 64 + mi * 16 + cr + j;
        const int col = bn * 128 + wn * 64 + ni * 16 + cc;
        C[(size_t)row * 4096 + col] = f2bf(acc[mi][ni][j]);
      }
}

// ---------------------------------------------------------------------------
// K5: expanded[s][h][d] = post[h]*out[s][d] + sum_k comb[h][k]*hs[s][k][d]
__global__ __launch_bounds__(256) void k_expand(const float* __restrict__ hs,
                                                const unsigned short* __restrict__ outb,
                                                const float* __restrict__ gates,
                                                float* __restrict__ y) {
  const int s = blockIdx.x, tid = threadIdx.x;
  const float* g = gates + (size_t)s * MIXN;
  float post[4], cb[4][4];
#pragma unroll
  for (int h = 0; h < 4; h++) post[h] = g[4 + h];
#pragma unroll
  for (int h = 0; h < 4; h++)
#pragma unroll
    for (int k = 0; k < 4; k++) cb[h][k] = g[8 + h * 4 + k];

  const size_t base = (size_t)s * HC_N * H_DIM;
#pragma unroll
  for (int it = 0; it < 4; ++it) {
    const int d4 = it * 256 + tid;
    f32x4 hv[4];
#pragma unroll
    for (int k = 0; k < 4; k++)
      hv[k] = *(const f32x4*)(hs + base + (size_t)k * H_DIM + (size_t)d4 * 4);
    u16x4 ob = *(const u16x4*)(outb + (size_t)s * H_DIM + (size_t)d4 * 4);
    f32x4 o = {bf2f(ob[0]), bf2f(ob[1]), bf2f(ob[2]), bf2f(ob[3])};
#pragma unroll
    for (int h = 0; h < 4; h++) {
      f32x4 e = post[h] * o + cb[h][0] * hv[0] + cb[h][1] * hv[1] + cb[h][2] * hv[2] + cb[h][3] * hv[3];
      *(f32x4*)(y + base + (size_t)h * H_DIM + (size_t)d4 * 4) = e;
    }
  }
}

// ---------------------------------------------------------------------------
extern "C" void kernel_launch(void* const* d_in, const int* in_sizes, int n_in,
                              void* d_out, int out_size, void* d_ws, size_t ws_size,
                              hipStream_t stream) {
  const float* hs = (const float*)d_in[0];      // [1,4096,4,4096]
  const float* fn = (const float*)d_in[1];      // [24,16384]
  const float* hbase = (const float*)d_in[2];   // [24]
  const float* hscale = (const float*)d_in[3];  // [3]
  const float* nw = (const float*)d_in[4];      // [4096]
  const float* wi = (const float*)d_in[5];      // [4096,4096]
  float* y = (float*)d_out;                     // [1,4096,4,4096] fp32

  char* ws = (char*)d_ws;
  float* gates = (float*)(ws);                                  // 393216 B
  float* sumsqpart = (float*)(ws + 524288);                     // 4096*32*4 = 524288
  float* mixpart = (float*)(ws + 1048576);                      // 4096*32*24*4 = 12.6MB
  unsigned short* fnb = (unsigned short*)(ws + 13631488);       // 32*16384*2 = 1MB
  unsigned short* normed = (unsigned short*)(ws + 16777216);    // 32MB bf16
  unsigned short* wb = (unsigned short*)(ws + 50331648);        // 32MB bf16
  unsigned short* outb = (unsigned short*)(ws + 83886080);      // 32MB bf16
  // total ws use: ~112MB

  k_w2bf<<<8448, 256, 0, stream>>>(wi, wb, fn, fnb);
  k_mixgemm<<<dim3(32, 32), 256, 0, stream>>>(hs, fnb, mixpart, sumsqpart);
  k_gates<<<16, 256, 0, stream>>>(mixpart, sumsqpart, hbase, hscale, gates);
  k_reduce_norm<<<4096, 256, 0, stream>>>(hs, gates, nw, normed);
  k_gemm<<<dim3(32, 32), 256, 0, stream>>>(normed, wb, outb);
  k_expand<<<4096, 256, 0, stream>>>(hs, outb, gates, y);
}